// Round 5
// baseline (1679.809 us; speedup 1.0000x reference)
//
#include <hip/hip_runtime.h>

#define GLOBAL_AS __attribute__((address_space(1)))
#define LDS_AS    __attribute__((address_space(3)))

typedef int   i32x4  __attribute__((ext_vector_type(4)));
typedef int   i32x8  __attribute__((ext_vector_type(8)));
typedef float f32x16 __attribute__((ext_vector_type(16)));

// ---------- kernel 1: fused L2 normalize -> fp8 e4m3 of (x * 32 / ||row||) ----------
// audio rows then visual rows, contiguous fp8 output rows of 768 bytes.
__global__ __launch_bounds__(256) void l2norm_fp8_kernel(const float* __restrict__ audio,
                                                         const float* __restrict__ visual,
                                                         unsigned char* __restrict__ out) {
    const int gw = blockIdx.x * 4 + (threadIdx.x >> 6);  // global row 0..24575
    const int l  = threadIdx.x & 63;
    const float* src = (gw < 16384) ? (audio + (size_t)gw * 768)
                                    : (visual + ((size_t)gw - 16384) * 768);
    const float4* p = (const float4*)src;
    float4 a = p[l], b = p[l + 64], c = p[l + 128];
    float ss = a.x * a.x + a.y * a.y + a.z * a.z + a.w * a.w
             + b.x * b.x + b.y * b.y + b.z * b.z + b.w * b.w
             + c.x * c.x + c.y * c.y + c.z * c.z + c.w * c.w;
#pragma unroll
    for (int m = 1; m < 64; m <<= 1) ss += __shfl_xor(ss, m, 64);
    const float s = 32.0f / fmaxf(sqrtf(ss), 1e-12f);
    unsigned int* o = (unsigned int*)(out + (size_t)gw * 768);
    int d0 = __builtin_amdgcn_cvt_pk_fp8_f32(a.x * s, a.y * s, 0, false);
    d0     = __builtin_amdgcn_cvt_pk_fp8_f32(a.z * s, a.w * s, d0, true);
    int d1 = __builtin_amdgcn_cvt_pk_fp8_f32(b.x * s, b.y * s, 0, false);
    d1     = __builtin_amdgcn_cvt_pk_fp8_f32(b.z * s, b.w * s, d1, true);
    int d2 = __builtin_amdgcn_cvt_pk_fp8_f32(c.x * s, c.y * s, 0, false);
    d2     = __builtin_amdgcn_cvt_pk_fp8_f32(c.z * s, c.w * s, d2, true);
    o[l] = (unsigned int)d0; o[l + 64] = (unsigned int)d1; o[l + 128] = (unsigned int)d2;
}

// ---------- kernel 2: 256x256-tile fp8 GEMM (mfma_scale 32x32x64), fused row-max ----
// A: 16384x768 fp8, V: 8192x768 fp8 (row stride 768 B). Block = 256 audio rows x one
// clip (256 visual rows). 512 threads = 8 waves (2 wm x 4 wn); wave tile 128x64.
// LDS 64 KiB: A dbuf{0,1} x half{0,1} @ (buf*2+h)*8192 ; B same @ +32768.
// Half-tile = 128 rows x 64 fp8 (64 B/row). Bank swizzle for 64B rows:
//   phys_cb = cb ^ (((row>>1)&3)<<4)  -> rows 0..7 hit 8 distinct granules.
// Stage: one global_load_lds(16B)/thread/half-tile, linear LDS dest, inverse-
// swizzled global source (both-sides-or-neither). 2 barriers + vmcnt(4)/tile.

#define STAGE(KT) do {                                                                \
    const size_t _ko = (size_t)(KT) * 64;                                             \
    char* _da = smem + ((KT) & 1) * 16384 + tid * 16;                                 \
    __builtin_amdgcn_global_load_lds((GLOBAL_AS void*)(aStage + _ko),                 \
                                     (LDS_AS void*)(_da), 16, 0, 0);                  \
    __builtin_amdgcn_global_load_lds((GLOBAL_AS void*)(aStage + 98304 + _ko),         \
                                     (LDS_AS void*)(_da + 8192), 16, 0, 0);           \
    char* _dv = _da + 32768;                                                          \
    __builtin_amdgcn_global_load_lds((GLOBAL_AS void*)(vStage + _ko),                 \
                                     (LDS_AS void*)(_dv), 16, 0, 0);                  \
    __builtin_amdgcn_global_load_lds((GLOBAL_AS void*)(vStage + 98304 + _ko),         \
                                     (LDS_AS void*)(_dv + 8192), 16, 0, 0);           \
  } while (0)

__device__ __forceinline__ i32x8 rd_frag(const char* smem, int off) {
    i32x4 lo = *(const i32x4*)(smem + off);
    i32x4 hi = *(const i32x4*)(smem + (off ^ 16));
    return __builtin_shufflevector(lo, hi, 0, 1, 2, 3, 4, 5, 6, 7);
}

__global__ __launch_bounds__(512, 4) void gemm_max_kernel(
    const unsigned char* __restrict__ A, const unsigned char* __restrict__ V,
    float* __restrict__ rowmax) {
    __shared__ __align__(1024) char smem[65536];

    const int tid = threadIdx.x;
    const int l   = tid & 63;
    const int wid = tid >> 6;
    const int wm  = wid >> 2;      // 0..1 : 128-row half of A tile
    const int wn  = wid & 3;       // 0..3 : 64-col slice of B tile
    const int lo5 = l & 31;
    const int hi  = l >> 5;
    // read addressing: logical k-bytes hi*32 (+16 via ^16), swizzled by row
    const int physA = (hi * 32) ^ (((lo5 >> 1) & 3) << 4);
    const int aOffL = lo5 * 64 + physA;                    // + mi*2048 (32 rows)
    const int bOffL = (wn & 1) * 4096 + lo5 * 64 + physA;  // + ni*2048

    const int bx  = blockIdx.x;                  // 2048 blocks, %8==0 -> bijective
    const int swz = (bx & 7) * 256 + (bx >> 3);  // XCD-aware swizzle
    const int rowBlk = swz >> 5;                 // 0..63
    const int clip   = swz & 31;                 // 0..31
    const size_t aRow0 = (size_t)rowBlk * 256;
    const size_t vRow0 = (size_t)clip * 256;

    // stage source: LDS linear (row = tid>>2, c4 = tid&3) <- global granule c4 ^ ((row>>1)&3)
    const int sr  = tid >> 2;                                    // 0..127
    const int scb = (((tid & 3) ^ ((sr >> 1) & 3)) << 4);
    const unsigned char* aStage = A + (aRow0 + sr) * 768 + scb;
    const unsigned char* vStage = V + (vRow0 + sr) * 768 + scb;

    f32x16 acc[4][2];
#pragma unroll
    for (int i = 0; i < 4; ++i)
#pragma unroll
        for (int j = 0; j < 2; ++j)
#pragma unroll
            for (int r = 0; r < 16; ++r) acc[i][j][r] = 0.0f;

    // prologue: stage kt0 + kt1 (8 loads/wave); wait own kt0 (4 newest in flight)
    STAGE(0); STAGE(1);
    asm volatile("s_waitcnt vmcnt(4)" ::: "memory");
    __builtin_amdgcn_s_barrier();

#pragma unroll 1
    for (int kt = 0; kt < 12; ++kt) {
        const int AbOff = (kt & 1) * 16384 + wm * 8192;
        const int BbOff = 32768 + (kt & 1) * 16384 + (wn >> 1) * 8192 + bOffL;
        i32x8 fa0 = rd_frag(smem, AbOff + aOffL);
        i32x8 fa1 = rd_frag(smem, AbOff + aOffL + 2048);
        i32x8 fa2 = rd_frag(smem, AbOff + aOffL + 4096);
        i32x8 fa3 = rd_frag(smem, AbOff + aOffL + 6144);
        i32x8 fb0 = rd_frag(smem, BbOff);
        i32x8 fb1 = rd_frag(smem, BbOff + 2048);
        asm volatile("s_waitcnt lgkmcnt(0)" ::: "memory");
        __builtin_amdgcn_sched_barrier(0);
        __builtin_amdgcn_s_setprio(1);
        acc[0][0] = __builtin_amdgcn_mfma_scale_f32_32x32x64_f8f6f4(
            fa0, fb0, acc[0][0], 0, 0, 0, 0x7F7F7F7F, 0, 0x7F7F7F7F);
        acc[1][0] = __builtin_amdgcn_mfma_scale_f32_32x32x64_f8f6f4(
            fa1, fb0, acc[1][0], 0, 0, 0, 0x7F7F7F7F, 0, 0x7F7F7F7F);
        acc[2][0] = __builtin_amdgcn_mfma_scale_f32_32x32x64_f8f6f4(
            fa2, fb0, acc[2][0], 0, 0, 0, 0x7F7F7F7F, 0, 0x7F7F7F7F);
        acc[3][0] = __builtin_amdgcn_mfma_scale_f32_32x32x64_f8f6f4(
            fa3, fb0, acc[3][0], 0, 0, 0, 0x7F7F7F7F, 0, 0x7F7F7F7F);
        __builtin_amdgcn_s_setprio(0);
        __builtin_amdgcn_sched_barrier(0);
        __builtin_amdgcn_s_barrier();   // P0 end: all reads of buf done (lgkm=0 above)
        if (kt < 10) { STAGE(kt + 2); }
        __builtin_amdgcn_s_setprio(1);
        acc[0][1] = __builtin_amdgcn_mfma_scale_f32_32x32x64_f8f6f4(
            fa0, fb1, acc[0][1], 0, 0, 0, 0x7F7F7F7F, 0, 0x7F7F7F7F);
        acc[1][1] = __builtin_amdgcn_mfma_scale_f32_32x32x64_f8f6f4(
            fa1, fb1, acc[1][1], 0, 0, 0, 0x7F7F7F7F, 0, 0x7F7F7F7F);
        acc[2][1] = __builtin_amdgcn_mfma_scale_f32_32x32x64_f8f6f4(
            fa2, fb1, acc[2][1], 0, 0, 0, 0x7F7F7F7F, 0, 0x7F7F7F7F);
        acc[3][1] = __builtin_amdgcn_mfma_scale_f32_32x32x64_f8f6f4(
            fa3, fb1, acc[3][1], 0, 0, 0, 0x7F7F7F7F, 0, 0x7F7F7F7F);
        __builtin_amdgcn_s_setprio(0);
        __builtin_amdgcn_sched_barrier(0);
        if (kt < 10)       asm volatile("s_waitcnt vmcnt(4)" ::: "memory");
        else if (kt == 10) asm volatile("s_waitcnt vmcnt(0)" ::: "memory");
        __builtin_amdgcn_s_barrier();   // P1 end: next tile staged & visible
    }

    // epilogue: fused row-max over the clip's 256 visual cols.
    // C/D layout (32x32): col = lane&31, row = (r&3) + 8*(r>>2) + 4*hi
    __syncthreads();
    float* pm = (float*)smem;  // [256 rows][4 wn] partial maxes
#pragma unroll
    for (int mi = 0; mi < 4; ++mi) {
#pragma unroll
        for (int r = 0; r < 16; ++r) {
            float m = fmaxf(acc[mi][0][r], acc[mi][1][r]);
            m = fmaxf(m, __shfl_xor(m, 1, 64));
            m = fmaxf(m, __shfl_xor(m, 2, 64));
            m = fmaxf(m, __shfl_xor(m, 4, 64));
            m = fmaxf(m, __shfl_xor(m, 8, 64));
            m = fmaxf(m, __shfl_xor(m, 16, 64));
            if (lo5 == 0) {
                const int row = wm * 128 + mi * 32 + 4 * hi + (r & 3) + 8 * (r >> 2);
                pm[row * 4 + wn] = m;
            }
        }
    }
    __syncthreads();
    if (tid < 256) {
        float m = fmaxf(fmaxf(pm[tid * 4], pm[tid * 4 + 1]),
                        fmaxf(pm[tid * 4 + 2], pm[tid * 4 + 3]));
        rowmax[(size_t)clip * 16384 + aRow0 + tid] = m;
    }
}

// ---------- kernel 3: mean over 512 audio rows -> clip_sims[32][32] ----------
// folds 1/temp (x10), 1/512 mean, and 1/1024 fp8 pre-scale compensation (32*32).
__global__ __launch_bounds__(256) void reduce_mean_kernel(const float* __restrict__ rm,
                                                          float* __restrict__ clip) {
    const int b = blockIdx.x >> 5;
    const int c = blockIdx.x & 31;
    const int t = threadIdx.x;
    const float* p = rm + (size_t)c * 16384 + (size_t)b * 512;
    float s = p[t] + p[t + 256];
#pragma unroll
    for (int m = 1; m < 64; m <<= 1) s += __shfl_xor(s, m, 64);
    __shared__ float wsum[4];
    if ((t & 63) == 0) wsum[t >> 6] = s;
    __syncthreads();
    if (t == 0)
        clip[b * 32 + c] = (wsum[0] + wsum[1] + wsum[2] + wsum[3]) * (1.0f / (51.2f * 1024.0f));
}

// ---------- kernel 4: log-softmax both ways on 32x32 + scalar loss ----------
__global__ __launch_bounds__(1024) void finalize_kernel(const float* __restrict__ clip,
                                                        float* __restrict__ out) {
    __shared__ float cs[32][33];
    __shared__ float rlse[32], clse[32];
    const int t = threadIdx.x;
    const int b = t >> 5, c = t & 31;
    cs[b][c] = clip[b * 32 + c];
    __syncthreads();
    if (t < 32) {
        float mx = -1e30f;
        for (int j = 0; j < 32; ++j) mx = fmaxf(mx, cs[t][j]);
        float s = 0.0f;
        for (int j = 0; j < 32; ++j) s += expf(cs[t][j] - mx);
        rlse[t] = mx + logf(s);
    } else if (t < 64) {
        const int cc = t - 32;
        float mx = -1e30f;
        for (int j = 0; j < 32; ++j) mx = fmaxf(mx, cs[j][cc]);
        float s = 0.0f;
        for (int j = 0; j < 32; ++j) s += expf(cs[j][cc] - mx);
        clse[cc] = mx + logf(s);
    }
    __syncthreads();
    if (t == 0) {
        float L = 0.0f;
        for (int i = 0; i < 32; ++i)
            L += -0.5f * (2.0f * cs[i][i] - rlse[i] - clse[i]);
        out[0] = L * (1.0f / 32.0f);
    }
}

extern "C" void kernel_launch(void* const* d_in, const int* in_sizes, int n_in,
                              void* d_out, int out_size, void* d_ws, size_t ws_size,
                              hipStream_t stream) {
    const float* audio  = (const float*)d_in[0];   // (32, 512, 768) f32
    const float* visual = (const float*)d_in[1];   // (32, 256, 768) f32

    unsigned char* aN = (unsigned char*)d_ws;                   // 16384*768 fp8
    unsigned char* vN = aN + (size_t)16384 * 768;               // 8192*768 fp8
    float* rowmax = (float*)(vN + (size_t)8192 * 768);          // 32*16384 f32
    float* clip   = rowmax + (size_t)32 * 16384;                // 1024 f32
    float* out    = (float*)d_out;

    l2norm_fp8_kernel<<<6144, 256, 0, stream>>>(audio, visual, aN);
    gemm_max_kernel<<<2048, 512, 0, stream>>>(aN, vN, rowmax);
    reduce_mean_kernel<<<1024, 256, 0, stream>>>(rowmax, clip);
    finalize_kernel<<<1, 1024, 0, stream>>>(clip, out);
}

// Round 6
// 228.204 us; speedup vs baseline: 7.3610x; 7.3610x over previous
//
#include <hip/hip_runtime.h>

#define GLOBAL_AS __attribute__((address_space(1)))
#define LDS_AS    __attribute__((address_space(3)))

typedef int   i32x4  __attribute__((ext_vector_type(4)));
typedef int   i32x8  __attribute__((ext_vector_type(8)));
typedef float f32x16 __attribute__((ext_vector_type(16)));

// ---------- kernel 1: fused L2 normalize -> fp8 e4m3 of (x * 32 / ||row||) ----------
// audio rows then visual rows, contiguous fp8 output rows of 768 bytes.
__global__ __launch_bounds__(256) void l2norm_fp8_kernel(const float* __restrict__ audio,
                                                         const float* __restrict__ visual,
                                                         unsigned char* __restrict__ out) {
    const int gw = blockIdx.x * 4 + (threadIdx.x >> 6);  // global row 0..24575
    const int l  = threadIdx.x & 63;
    const float* src = (gw < 16384) ? (audio + (size_t)gw * 768)
                                    : (visual + ((size_t)gw - 16384) * 768);
    const float4* p = (const float4*)src;
    float4 a = p[l], b = p[l + 64], c = p[l + 128];
    float ss = a.x * a.x + a.y * a.y + a.z * a.z + a.w * a.w
             + b.x * b.x + b.y * b.y + b.z * b.z + b.w * b.w
             + c.x * c.x + c.y * c.y + c.z * c.z + c.w * c.w;
#pragma unroll
    for (int m = 1; m < 64; m <<= 1) ss += __shfl_xor(ss, m, 64);
    const float s = 32.0f / fmaxf(sqrtf(ss), 1e-12f);
    unsigned int* o = (unsigned int*)(out + (size_t)gw * 768);
    int d0 = __builtin_amdgcn_cvt_pk_fp8_f32(a.x * s, a.y * s, 0, false);
    d0     = __builtin_amdgcn_cvt_pk_fp8_f32(a.z * s, a.w * s, d0, true);
    int d1 = __builtin_amdgcn_cvt_pk_fp8_f32(b.x * s, b.y * s, 0, false);
    d1     = __builtin_amdgcn_cvt_pk_fp8_f32(b.z * s, b.w * s, d1, true);
    int d2 = __builtin_amdgcn_cvt_pk_fp8_f32(c.x * s, c.y * s, 0, false);
    d2     = __builtin_amdgcn_cvt_pk_fp8_f32(c.z * s, c.w * s, d2, true);
    o[l] = (unsigned int)d0; o[l + 64] = (unsigned int)d1; o[l + 128] = (unsigned int)d2;
}

// ---------- kernel 2: 256x256-tile fp8 GEMM (mfma_scale 32x32x64), fused row-max ----
// A: 16384x768 fp8, V: 8192x768 fp8 (row stride 768 B). Block = 256 audio rows x one
// clip (256 visual rows). 512 threads = 8 waves (2 wm x 4 wn); wave tile 128x64.
// LDS 64 KiB: A dbuf{0,1} x half{0,1} @ (buf*2+h)*8192 ; B same @ +32768.
// Half-tile = 128 rows x 64 fp8 (64 B/row). Bank swizzle for 64B rows:
//   phys_cb = cb ^ (((row>>1)&3)<<4)  -> rows 0..7 hit 8 distinct granules.
// Stage: one global_load_lds(16B)/thread/half-tile, linear LDS dest, inverse-
// swizzled global source (both-sides-or-neither). 2 barriers + vmcnt(4)/tile.
// NOTE: __launch_bounds__ second arg MUST stay 2 — (512,4) caps VGPRs and
// spills the 128-float accumulator to scratch (R5: 8 GB HBM traffic, 5.5x slower).

#define STAGE(KT) do {                                                                \
    const size_t _ko = (size_t)(KT) * 64;                                             \
    char* _da = smem + ((KT) & 1) * 16384 + tid * 16;                                 \
    __builtin_amdgcn_global_load_lds((GLOBAL_AS void*)(aStage + _ko),                 \
                                     (LDS_AS void*)(_da), 16, 0, 0);                  \
    __builtin_amdgcn_global_load_lds((GLOBAL_AS void*)(aStage + 98304 + _ko),         \
                                     (LDS_AS void*)(_da + 8192), 16, 0, 0);           \
    char* _dv = _da + 32768;                                                          \
    __builtin_amdgcn_global_load_lds((GLOBAL_AS void*)(vStage + _ko),                 \
                                     (LDS_AS void*)(_dv), 16, 0, 0);                  \
    __builtin_amdgcn_global_load_lds((GLOBAL_AS void*)(vStage + 98304 + _ko),         \
                                     (LDS_AS void*)(_dv + 8192), 16, 0, 0);           \
  } while (0)

__device__ __forceinline__ i32x8 rd_frag(const char* smem, int off) {
    i32x4 lo = *(const i32x4*)(smem + off);
    i32x4 hi = *(const i32x4*)(smem + (off ^ 16));
    return __builtin_shufflevector(lo, hi, 0, 1, 2, 3, 4, 5, 6, 7);
}

__global__ __launch_bounds__(512, 2) void gemm_max_kernel(
    const unsigned char* __restrict__ A, const unsigned char* __restrict__ V,
    float* __restrict__ rowmax) {
    __shared__ __align__(1024) char smem[65536];

    const int tid = threadIdx.x;
    const int l   = tid & 63;
    const int wid = tid >> 6;
    const int wm  = wid >> 2;      // 0..1 : 128-row half of A tile
    const int wn  = wid & 3;       // 0..3 : 64-col slice of B tile
    const int lo5 = l & 31;
    const int hi  = l >> 5;
    // read addressing: logical k-bytes hi*32 (+16 via ^16), swizzled by row
    const int physA = (hi * 32) ^ (((lo5 >> 1) & 3) << 4);
    const int aOffL = lo5 * 64 + physA;                    // + mi*2048 (32 rows)
    const int bOffL = (wn & 1) * 4096 + lo5 * 64 + physA;  // + ni*2048

    const int bx  = blockIdx.x;                  // 2048 blocks, %8==0 -> bijective
    const int swz = (bx & 7) * 256 + (bx >> 3);  // XCD-aware swizzle
    const int rowBlk = swz >> 5;                 // 0..63
    const int clip   = swz & 31;                 // 0..31
    const size_t aRow0 = (size_t)rowBlk * 256;
    const size_t vRow0 = (size_t)clip * 256;

    // stage source: LDS linear (row = tid>>2, c4 = tid&3) <- global granule c4 ^ ((row>>1)&3)
    const int sr  = tid >> 2;                                    // 0..127
    const int scb = (((tid & 3) ^ ((sr >> 1) & 3)) << 4);
    const unsigned char* aStage = A + (aRow0 + sr) * 768 + scb;
    const unsigned char* vStage = V + (vRow0 + sr) * 768 + scb;

    f32x16 acc[4][2];
#pragma unroll
    for (int i = 0; i < 4; ++i)
#pragma unroll
        for (int j = 0; j < 2; ++j)
#pragma unroll
            for (int r = 0; r < 16; ++r) acc[i][j][r] = 0.0f;

    // prologue: stage kt0 + kt1 (8 loads/wave); wait own kt0 (4 newest in flight)
    STAGE(0); STAGE(1);
    asm volatile("s_waitcnt vmcnt(4)" ::: "memory");
    __builtin_amdgcn_s_barrier();

#pragma unroll 1
    for (int kt = 0; kt < 12; ++kt) {
        const int AbOff = (kt & 1) * 16384 + wm * 8192;
        const int BbOff = 32768 + (kt & 1) * 16384 + (wn >> 1) * 8192 + bOffL;
        i32x8 fa0 = rd_frag(smem, AbOff + aOffL);
        i32x8 fa1 = rd_frag(smem, AbOff + aOffL + 2048);
        i32x8 fa2 = rd_frag(smem, AbOff + aOffL + 4096);
        i32x8 fa3 = rd_frag(smem, AbOff + aOffL + 6144);
        i32x8 fb0 = rd_frag(smem, BbOff);
        i32x8 fb1 = rd_frag(smem, BbOff + 2048);
        asm volatile("s_waitcnt lgkmcnt(0)" ::: "memory");
        __builtin_amdgcn_sched_barrier(0);
        __builtin_amdgcn_s_setprio(1);
        acc[0][0] = __builtin_amdgcn_mfma_scale_f32_32x32x64_f8f6f4(
            fa0, fb0, acc[0][0], 0, 0, 0, 0x7F7F7F7F, 0, 0x7F7F7F7F);
        acc[1][0] = __builtin_amdgcn_mfma_scale_f32_32x32x64_f8f6f4(
            fa1, fb0, acc[1][0], 0, 0, 0, 0x7F7F7F7F, 0, 0x7F7F7F7F);
        acc[2][0] = __builtin_amdgcn_mfma_scale_f32_32x32x64_f8f6f4(
            fa2, fb0, acc[2][0], 0, 0, 0, 0x7F7F7F7F, 0, 0x7F7F7F7F);
        acc[3][0] = __builtin_amdgcn_mfma_scale_f32_32x32x64_f8f6f4(
            fa3, fb0, acc[3][0], 0, 0, 0, 0x7F7F7F7F, 0, 0x7F7F7F7F);
        __builtin_amdgcn_s_setprio(0);
        __builtin_amdgcn_sched_barrier(0);
        __builtin_amdgcn_s_barrier();   // P0 end: all reads of buf done (lgkm=0 above)
        if (kt < 10) { STAGE(kt + 2); }
        __builtin_amdgcn_s_setprio(1);
        acc[0][1] = __builtin_amdgcn_mfma_scale_f32_32x32x64_f8f6f4(
            fa0, fb1, acc[0][1], 0, 0, 0, 0x7F7F7F7F, 0, 0x7F7F7F7F);
        acc[1][1] = __builtin_amdgcn_mfma_scale_f32_32x32x64_f8f6f4(
            fa1, fb1, acc[1][1], 0, 0, 0, 0x7F7F7F7F, 0, 0x7F7F7F7F);
        acc[2][1] = __builtin_amdgcn_mfma_scale_f32_32x32x64_f8f6f4(
            fa2, fb1, acc[2][1], 0, 0, 0, 0x7F7F7F7F, 0, 0x7F7F7F7F);
        acc[3][1] = __builtin_amdgcn_mfma_scale_f32_32x32x64_f8f6f4(
            fa3, fb1, acc[3][1], 0, 0, 0, 0x7F7F7F7F, 0, 0x7F7F7F7F);
        __builtin_amdgcn_s_setprio(0);
        __builtin_amdgcn_sched_barrier(0);
        if (kt < 10)       asm volatile("s_waitcnt vmcnt(4)" ::: "memory");
        else if (kt == 10) asm volatile("s_waitcnt vmcnt(0)" ::: "memory");
        __builtin_amdgcn_s_barrier();   // P1 end: next tile staged & visible
    }

    // epilogue: fused row-max over the clip's 256 visual cols.
    // C/D layout (32x32): col = lane&31, row = (r&3) + 8*(r>>2) + 4*hi
    __syncthreads();
    float* pm = (float*)smem;  // [256 rows][4 wn] partial maxes
#pragma unroll
    for (int mi = 0; mi < 4; ++mi) {
#pragma unroll
        for (int r = 0; r < 16; ++r) {
            float m = fmaxf(acc[mi][0][r], acc[mi][1][r]);
            m = fmaxf(m, __shfl_xor(m, 1, 64));
            m = fmaxf(m, __shfl_xor(m, 2, 64));
            m = fmaxf(m, __shfl_xor(m, 4, 64));
            m = fmaxf(m, __shfl_xor(m, 8, 64));
            m = fmaxf(m, __shfl_xor(m, 16, 64));
            if (lo5 == 0) {
                const int row = wm * 128 + mi * 32 + 4 * hi + (r & 3) + 8 * (r >> 2);
                pm[row * 4 + wn] = m;
            }
        }
    }
    __syncthreads();
    if (tid < 256) {
        float m = fmaxf(fmaxf(pm[tid * 4], pm[tid * 4 + 1]),
                        fmaxf(pm[tid * 4 + 2], pm[tid * 4 + 3]));
        rowmax[(size_t)clip * 16384 + aRow0 + tid] = m;
    }
}

// ---------- kernel 3: mean over 512 audio rows -> clip_sims[32][32] ----------
// folds 1/temp (x10), 1/512 mean, and 1/1024 fp8 pre-scale compensation (32*32).
__global__ __launch_bounds__(256) void reduce_mean_kernel(const float* __restrict__ rm,
                                                          float* __restrict__ clip) {
    const int b = blockIdx.x >> 5;
    const int c = blockIdx.x & 31;
    const int t = threadIdx.x;
    const float* p = rm + (size_t)c * 16384 + (size_t)b * 512;
    float s = p[t] + p[t + 256];
#pragma unroll
    for (int m = 1; m < 64; m <<= 1) s += __shfl_xor(s, m, 64);
    __shared__ float wsum[4];
    if ((t & 63) == 0) wsum[t >> 6] = s;
    __syncthreads();
    if (t == 0)
        clip[b * 32 + c] = (wsum[0] + wsum[1] + wsum[2] + wsum[3]) * (1.0f / (51.2f * 1024.0f));
}

// ---------- kernel 4: log-softmax both ways on 32x32 + scalar loss ----------
__global__ __launch_bounds__(1024) void finalize_kernel(const float* __restrict__ clip,
                                                        float* __restrict__ out) {
    __shared__ float cs[32][33];
    __shared__ float rlse[32], clse[32];
    const int t = threadIdx.x;
    const int b = t >> 5, c = t & 31;
    cs[b][c] = clip[b * 32 + c];
    __syncthreads();
    if (t < 32) {
        float mx = -1e30f;
        for (int j = 0; j < 32; ++j) mx = fmaxf(mx, cs[t][j]);
        float s = 0.0f;
        for (int j = 0; j < 32; ++j) s += expf(cs[t][j] - mx);
        rlse[t] = mx + logf(s);
    } else if (t < 64) {
        const int cc = t - 32;
        float mx = -1e30f;
        for (int j = 0; j < 32; ++j) mx = fmaxf(mx, cs[j][cc]);
        float s = 0.0f;
        for (int j = 0; j < 32; ++j) s += expf(cs[j][cc] - mx);
        clse[cc] = mx + logf(s);
    }
    __syncthreads();
    if (t == 0) {
        float L = 0.0f;
        for (int i = 0; i < 32; ++i)
            L += -0.5f * (2.0f * cs[i][i] - rlse[i] - clse[i]);
        out[0] = L * (1.0f / 32.0f);
    }
}

extern "C" void kernel_launch(void* const* d_in, const int* in_sizes, int n_in,
                              void* d_out, int out_size, void* d_ws, size_t ws_size,
                              hipStream_t stream) {
    const float* audio  = (const float*)d_in[0];   // (32, 512, 768) f32
    const float* visual = (const float*)d_in[1];   // (32, 256, 768) f32

    unsigned char* aN = (unsigned char*)d_ws;                   // 16384*768 fp8
    unsigned char* vN = aN + (size_t)16384 * 768;               // 8192*768 fp8
    float* rowmax = (float*)(vN + (size_t)8192 * 768);          // 32*16384 f32
    float* clip   = rowmax + (size_t)32 * 16384;                // 1024 f32
    float* out    = (float*)d_out;

    l2norm_fp8_kernel<<<6144, 256, 0, stream>>>(audio, visual, aN);
    gemm_max_kernel<<<2048, 512, 0, stream>>>(aN, vN, rowmax);
    reduce_mean_kernel<<<1024, 256, 0, stream>>>(rowmax, clip);
    finalize_kernel<<<1, 1024, 0, stream>>>(clip, out);
}

// Round 7
// 218.866 us; speedup vs baseline: 7.6751x; 1.0427x over previous
//
#include <hip/hip_runtime.h>

#define GLOBAL_AS __attribute__((address_space(1)))
#define LDS_AS    __attribute__((address_space(3)))

typedef int   i32x4  __attribute__((ext_vector_type(4)));
typedef int   i32x8  __attribute__((ext_vector_type(8)));
typedef float f32x16 __attribute__((ext_vector_type(16)));

// ---------- kernel 1: fused L2 normalize -> fp8 e4m3 of (x * 32 / ||row||) ----------
__global__ __launch_bounds__(256) void l2norm_fp8_kernel(const float* __restrict__ audio,
                                                         const float* __restrict__ visual,
                                                         unsigned char* __restrict__ out) {
    const int gw = blockIdx.x * 4 + (threadIdx.x >> 6);  // global row 0..24575
    const int l  = threadIdx.x & 63;
    const float* src = (gw < 16384) ? (audio + (size_t)gw * 768)
                                    : (visual + ((size_t)gw - 16384) * 768);
    const float4* p = (const float4*)src;
    float4 a = p[l], b = p[l + 64], c = p[l + 128];
    float ss = a.x * a.x + a.y * a.y + a.z * a.z + a.w * a.w
             + b.x * b.x + b.y * b.y + b.z * b.z + b.w * b.w
             + c.x * c.x + c.y * c.y + c.z * c.z + c.w * c.w;
#pragma unroll
    for (int m = 1; m < 64; m <<= 1) ss += __shfl_xor(ss, m, 64);
    const float s = 32.0f / fmaxf(sqrtf(ss), 1e-12f);
    unsigned int* o = (unsigned int*)(out + (size_t)gw * 768);
    int d0 = __builtin_amdgcn_cvt_pk_fp8_f32(a.x * s, a.y * s, 0, false);
    d0     = __builtin_amdgcn_cvt_pk_fp8_f32(a.z * s, a.w * s, d0, true);
    int d1 = __builtin_amdgcn_cvt_pk_fp8_f32(b.x * s, b.y * s, 0, false);
    d1     = __builtin_amdgcn_cvt_pk_fp8_f32(b.z * s, b.w * s, d1, true);
    int d2 = __builtin_amdgcn_cvt_pk_fp8_f32(c.x * s, c.y * s, 0, false);
    d2     = __builtin_amdgcn_cvt_pk_fp8_f32(c.z * s, c.w * s, d2, true);
    o[l] = (unsigned int)d0; o[l + 64] = (unsigned int)d1; o[l + 128] = (unsigned int)d2;
}

// ---------- kernel 2: 256x128-tile fp8 GEMM (mfma_scale 32x32x64), fused row-max ----
// A: 16384x768 fp8, V: 8192x768 fp8. Block = 256 threads (4 waves, grid 2wm x 2wn),
// tile 256 audio rows x 128 visual rows (half clip). Wave tile 128x64.
// LDS 48 KiB, frag-slot layout (conflict-free by construction):
//   A[16KB/buf]: off/16 = wm<<9 | mi<<7 | half<<6 | lane   (lane = hi*32+lo5)
//   B[ 8KB/buf]: off/16 = wn<<8 | ni<<7 | half<<6 | lane
//   element at (row = 32*(idx>>7) + (idx&31), kb = hi*32 + half*16)
// -> every ds_read_b128 is base + lane*16 (linear, 0 conflicts); staging dest is
// linear too; the permutation lives entirely in the per-lane GLOBAL source addr.
// 2 blocks/CU (96KB LDS, ~210 regs @ 2 waves/SIMD) break the barrier lockstep.
// NOTE: acc = 128 AGPRs; launch_bounds min-waves must stay 2 (R5: 4 -> spill, 8GB
// scratch traffic, 5.5x slower).

#define STAGE(KT) do {                                                                \
    const size_t _ko = (size_t)(KT) * 64;                                             \
    char* _dA = smem + ((KT) & 1) * 24576 + tid * 16;                                 \
    __builtin_amdgcn_global_load_lds((GLOBAL_AS void*)(aStage + _ko),                 \
                                     (LDS_AS void*)(_dA), 16, 0, 0);                  \
    __builtin_amdgcn_global_load_lds((GLOBAL_AS void*)(aStage + 49152 + _ko),         \
                                     (LDS_AS void*)(_dA + 4096), 16, 0, 0);           \
    __builtin_amdgcn_global_load_lds((GLOBAL_AS void*)(aStage + 98304 + _ko),         \
                                     (LDS_AS void*)(_dA + 8192), 16, 0, 0);           \
    __builtin_amdgcn_global_load_lds((GLOBAL_AS void*)(aStage + 147456 + _ko),        \
                                     (LDS_AS void*)(_dA + 12288), 16, 0, 0);          \
    char* _dB = _dA + 16384;                                                          \
    __builtin_amdgcn_global_load_lds((GLOBAL_AS void*)(vStage + _ko),                 \
                                     (LDS_AS void*)(_dB), 16, 0, 0);                  \
    __builtin_amdgcn_global_load_lds((GLOBAL_AS void*)(vStage + 49152 + _ko),         \
                                     (LDS_AS void*)(_dB + 4096), 16, 0, 0);           \
  } while (0)

__device__ __forceinline__ i32x8 rd_frag2(const char* p) {
    i32x4 lo = *(const i32x4*)(p);
    i32x4 hi = *(const i32x4*)(p + 1024);
    return __builtin_shufflevector(lo, hi, 0, 1, 2, 3, 4, 5, 6, 7);
}

__global__ __launch_bounds__(256, 2) void gemm_max_kernel(
    const unsigned char* __restrict__ A, const unsigned char* __restrict__ V,
    float* __restrict__ rowhalf) {
    __shared__ __align__(1024) char smem[49152];

    const int tid = threadIdx.x;
    const int l   = tid & 63;
    const int wid = tid >> 6;
    const int wm  = wid >> 1;      // 0..1 : 128-row half of A tile
    const int wn  = wid & 1;       // 0..1 : 64-col slice of B tile
    const int lo5 = l & 31;
    const int hi  = l >> 5;

    const int bx  = blockIdx.x;                  // 4096 blocks, %8==0 -> bijective
    const int swz = (bx & 7) * 512 + (bx >> 3);  // XCD-aware swizzle
    const int rowBlk = swz >> 6;                 // 0..63
    const int colBlk = swz & 63;                 // 0..63 (clip = colBlk>>1)
    const size_t aRow0 = (size_t)rowBlk * 256;
    const size_t vRow0 = (size_t)colBlk * 128;

    // staging source (per-lane permutation; see layout comment):
    //   idx = r*256 + tid ; row = r*64 + 32*(tid>>7) + (tid&31)
    //   kb  = ((tid>>5)&1)*32 + ((tid>>6)&1)*16   (r-independent)
    const int rowT = 32 * (tid >> 7) + (tid & 31);
    const int kbT  = ((tid >> 5) & 1) * 32 + ((tid >> 6) & 1) * 16;
    const unsigned char* aStage = A + (aRow0 + rowT) * 768 + kbT;
    const unsigned char* vStage = V + (vRow0 + rowT) * 768 + kbT;

    // reader bases (within current buf): linear lane*16 reads
    const int aBase0 = wm * 8192 + l * 16;
    const int bBase0 = 16384 + wn * 4096 + l * 16;

    f32x16 acc[4][2];
#pragma unroll
    for (int i = 0; i < 4; ++i)
#pragma unroll
        for (int j = 0; j < 2; ++j)
#pragma unroll
            for (int r = 0; r < 16; ++r) acc[i][j][r] = 0.0f;

    // prologue: stage kt0 + kt1 (12 loads/thread); wait kt0 (6 newest in flight)
    STAGE(0); STAGE(1);
    asm volatile("s_waitcnt vmcnt(6)" ::: "memory");
    __builtin_amdgcn_s_barrier();

#pragma unroll 1
    for (int kt = 0; kt < 12; ++kt) {
        const char* aB = smem + (kt & 1) * 24576 + aBase0;
        const char* bB = smem + (kt & 1) * 24576 + bBase0;
        i32x8 fa0 = rd_frag2(aB);
        i32x8 fa1 = rd_frag2(aB + 2048);
        i32x8 fa2 = rd_frag2(aB + 4096);
        i32x8 fa3 = rd_frag2(aB + 6144);
        i32x8 fb0 = rd_frag2(bB);
        i32x8 fb1 = rd_frag2(bB + 2048);
        asm volatile("s_waitcnt lgkmcnt(0)" ::: "memory");
        __builtin_amdgcn_sched_barrier(0);
        __builtin_amdgcn_s_setprio(1);
        acc[0][0] = __builtin_amdgcn_mfma_scale_f32_32x32x64_f8f6f4(
            fa0, fb0, acc[0][0], 0, 0, 0, 0x7F7F7F7F, 0, 0x7F7F7F7F);
        acc[1][0] = __builtin_amdgcn_mfma_scale_f32_32x32x64_f8f6f4(
            fa1, fb0, acc[1][0], 0, 0, 0, 0x7F7F7F7F, 0, 0x7F7F7F7F);
        acc[2][0] = __builtin_amdgcn_mfma_scale_f32_32x32x64_f8f6f4(
            fa2, fb0, acc[2][0], 0, 0, 0, 0x7F7F7F7F, 0, 0x7F7F7F7F);
        acc[3][0] = __builtin_amdgcn_mfma_scale_f32_32x32x64_f8f6f4(
            fa3, fb0, acc[3][0], 0, 0, 0, 0x7F7F7F7F, 0, 0x7F7F7F7F);
        __builtin_amdgcn_s_setprio(0);
        __builtin_amdgcn_sched_barrier(0);
        __builtin_amdgcn_s_barrier();   // all reads of this buf done (lgkm=0 above)
        if (kt < 10) { STAGE(kt + 2); }
        __builtin_amdgcn_s_setprio(1);
        acc[0][1] = __builtin_amdgcn_mfma_scale_f32_32x32x64_f8f6f4(
            fa0, fb1, acc[0][1], 0, 0, 0, 0x7F7F7F7F, 0, 0x7F7F7F7F);
        acc[1][1] = __builtin_amdgcn_mfma_scale_f32_32x32x64_f8f6f4(
            fa1, fb1, acc[1][1], 0, 0, 0, 0x7F7F7F7F, 0, 0x7F7F7F7F);
        acc[2][1] = __builtin_amdgcn_mfma_scale_f32_32x32x64_f8f6f4(
            fa2, fb1, acc[2][1], 0, 0, 0, 0x7F7F7F7F, 0, 0x7F7F7F7F);
        acc[3][1] = __builtin_amdgcn_mfma_scale_f32_32x32x64_f8f6f4(
            fa3, fb1, acc[3][1], 0, 0, 0, 0x7F7F7F7F, 0, 0x7F7F7F7F);
        __builtin_amdgcn_s_setprio(0);
        __builtin_amdgcn_sched_barrier(0);
        if (kt < 10)       asm volatile("s_waitcnt vmcnt(6)" ::: "memory");
        else if (kt == 10) asm volatile("s_waitcnt vmcnt(0)" ::: "memory");
        __builtin_amdgcn_s_barrier();   // next tile staged & visible
    }

    // epilogue: fused row-max over this block's 128 visual cols.
    // C/D layout (32x32): col = lane&31, row = (r&3) + 8*(r>>2) + 4*hi
    __syncthreads();
    float* pm = (float*)smem;  // [256 rows][2 wn] partial maxes
#pragma unroll
    for (int mi = 0; mi < 4; ++mi) {
#pragma unroll
        for (int r = 0; r < 16; ++r) {
            float m = fmaxf(acc[mi][0][r], acc[mi][1][r]);
            m = fmaxf(m, __shfl_xor(m, 1, 64));
            m = fmaxf(m, __shfl_xor(m, 2, 64));
            m = fmaxf(m, __shfl_xor(m, 4, 64));
            m = fmaxf(m, __shfl_xor(m, 8, 64));
            m = fmaxf(m, __shfl_xor(m, 16, 64));
            if (lo5 == 0) {
                const int row = wm * 128 + mi * 32 + 4 * hi + (r & 3) + 8 * (r >> 2);
                pm[row * 2 + wn] = m;
            }
        }
    }
    __syncthreads();
    {
        float m = fmaxf(pm[tid * 2], pm[tid * 2 + 1]);
        rowhalf[(size_t)colBlk * 16384 + aRow0 + tid] = m;
    }
}

// ---------- kernel 3: combine halves (max) + mean over 512 rows -> clip_sims ----------
// folds 1/temp (x10), 1/512 mean, and 1/1024 fp8 pre-scale compensation (32*32).
__global__ __launch_bounds__(256) void reduce_mean_kernel(const float* __restrict__ rh,
                                                          float* __restrict__ clip) {
    const int b = blockIdx.x >> 5;
    const int c = blockIdx.x & 31;
    const int t = threadIdx.x;
    const float* p0 = rh + (size_t)(c * 2) * 16384 + (size_t)b * 512;
    const float* p1 = p0 + 16384;
    float s = fmaxf(p0[t], p1[t]) + fmaxf(p0[t + 256], p1[t + 256]);
#pragma unroll
    for (int m = 1; m < 64; m <<= 1) s += __shfl_xor(s, m, 64);
    __shared__ float wsum[4];
    if ((t & 63) == 0) wsum[t >> 6] = s;
    __syncthreads();
    if (t == 0)
        clip[b * 32 + c] = (wsum[0] + wsum[1] + wsum[2] + wsum[3]) * (1.0f / (51.2f * 1024.0f));
}

// ---------- kernel 4: log-softmax both ways on 32x32 + scalar loss ----------
__global__ __launch_bounds__(1024) void finalize_kernel(const float* __restrict__ clip,
                                                        float* __restrict__ out) {
    __shared__ float cs[32][33];
    __shared__ float rlse[32], clse[32];
    const int t = threadIdx.x;
    const int b = t >> 5, c = t & 31;
    cs[b][c] = clip[b * 32 + c];
    __syncthreads();
    if (t < 32) {
        float mx = -1e30f;
        for (int j = 0; j < 32; ++j) mx = fmaxf(mx, cs[t][j]);
        float s = 0.0f;
        for (int j = 0; j < 32; ++j) s += expf(cs[t][j] - mx);
        rlse[t] = mx + logf(s);
    } else if (t < 64) {
        const int cc = t - 32;
        float mx = -1e30f;
        for (int j = 0; j < 32; ++j) mx = fmaxf(mx, cs[j][cc]);
        float s = 0.0f;
        for (int j = 0; j < 32; ++j) s += expf(cs[j][cc] - mx);
        clse[cc] = mx + logf(s);
    }
    __syncthreads();
    if (t == 0) {
        float L = 0.0f;
        for (int i = 0; i < 32; ++i)
            L += -0.5f * (2.0f * cs[i][i] - rlse[i] - clse[i]);
        out[0] = L * (1.0f / 32.0f);
    }
}

extern "C" void kernel_launch(void* const* d_in, const int* in_sizes, int n_in,
                              void* d_out, int out_size, void* d_ws, size_t ws_size,
                              hipStream_t stream) {
    const float* audio  = (const float*)d_in[0];   // (32, 512, 768) f32
    const float* visual = (const float*)d_in[1];   // (32, 256, 768) f32

    unsigned char* aN = (unsigned char*)d_ws;                   // 16384*768 fp8
    unsigned char* vN = aN + (size_t)16384 * 768;               // 8192*768 fp8
    float* rowhalf = (float*)(vN + (size_t)8192 * 768);         // 64*16384 f32
    float* clip    = rowhalf + (size_t)64 * 16384;              // 1024 f32
    float* out     = (float*)d_out;

    l2norm_fp8_kernel<<<6144, 256, 0, stream>>>(audio, visual, aN);
    gemm_max_kernel<<<4096, 256, 0, stream>>>(aN, vN, rowhalf);
    reduce_mean_kernel<<<1024, 256, 0, stream>>>(rowhalf, clip);
    finalize_kernel<<<1, 1024, 0, stream>>>(clip, out);
}